// Round 6
// baseline (1631.685 us; speedup 1.0000x reference)
//
#include <hip/hip_runtime.h>
#include <hip/hip_bf16.h>

#define DIM 384
#define HEADS 12
#define NTOK 49
#define TOKENS 3137
#define M_ATTN 100352   // 32*64*49 window rows
#define M_FULL 100384   // 32*3137 token rows
#define M_PAD  100480   // 785*128
#define SCALEQ 0.17677669529663687f

typedef __attribute__((ext_vector_type(8))) short s8v;
typedef __attribute__((ext_vector_type(4))) float f4v;
typedef unsigned short u16;

__device__ __forceinline__ float b2f(int s) {
  union { unsigned u; float f; } c; c.u = ((unsigned)(s & 0xffff)) << 16; return c.f;
}
__device__ __forceinline__ u16 f2b(float f) {
  __hip_bfloat16 h = __float2bfloat16(f);
  return *reinterpret_cast<u16*>(&h);
}
__device__ __forceinline__ void gload16(const void* g, void* l) {
  __builtin_amdgcn_global_load_lds((const __attribute__((address_space(1))) void*)g,
                                   (__attribute__((address_space(3))) void*)l, 16, 0, 0);
}
__device__ __forceinline__ float gelu_f(float val) {
  // gelu(x) ~= x * sigmoid(1.5957691x + 0.0713548x^3), |err|<3e-3
  float u = __builtin_fmaf(0.0713548163f * val, val * val, 1.5957691216f * val);
  return val * __builtin_amdgcn_rcpf(1.0f + __expf(-u));
}

// ---------------- weight convert: f32 -> bf16, transposed to [N][K] ----------------
__global__ void k_convert(const float* __restrict__ qkv_w, const float* __restrict__ qkv_b,
                          const float* __restrict__ proj_w, const float* __restrict__ fc1_w,
                          const float* __restrict__ fc2_w,
                          u16* __restrict__ wt_qkv, float* __restrict__ qkvb_s,
                          u16* __restrict__ wt_proj, u16* __restrict__ wt_fc1,
                          u16* __restrict__ wt_fc2) {
  int i = blockIdx.x * 256 + threadIdx.x;
  if (i < 1152 * 384) { int n = i / 384, k = i % 384;
    float v = qkv_w[(size_t)k * 1152 + n]; if (n < 384) v *= SCALEQ; wt_qkv[i] = f2b(v); }
  if (i < 1152) qkvb_s[i] = qkv_b[i] * (i < 384 ? SCALEQ : 1.0f);
  if (i < 384 * 384) { int n = i / 384, k = i % 384; wt_proj[i] = f2b(proj_w[(size_t)k * 384 + n]); }
  if (i < 1536 * 384) { int n = i / 384, k = i % 384; wt_fc1[i] = f2b(fc1_w[(size_t)k * 1536 + n]); }
  if (i < 384 * 1536) { int n = i / 1536, k = i % 1536; wt_fc2[i] = f2b(fc2_w[(size_t)k * 384 + n]); }
}

// ---------------- ADD table: bias + shift mask per window class ----------------
__global__ void k_addtab(const float* __restrict__ rpb, float* __restrict__ ADD) {
  int idx = blockIdx.x * 256 + threadIdx.x;
  if (idx >= 4 * HEADS * NTOK * NTOK) return;
  int j = idx % NTOK, t = idx / NTOK;
  int i = t % NTOK; t /= NTOK;
  int h = t % HEADS; int cls = t / HEADS;
  int ii = i / 7, jj = i % 7, ji = j / 7, j2 = j % 7;
  int rpi = (ii - ji + 6) * 13 + (jj - j2 + 6);
  float v = rpb[rpi * HEADS + h];
  int rh = (cls & 2) ? (ii < 4 ? 1 : 2) : 0;
  int rw = (cls & 1) ? (jj < 4 ? 1 : 2) : 0;
  int sh = (cls & 2) ? (ji < 4 ? 1 : 2) : 0;
  int sw = (cls & 1) ? (j2 < 4 ? 1 : 2) : 0;
  if (rh != sh || rw != sw) v -= 100.0f;
  ADD[idx] = v;
}

// ---------------- LN1 + roll(-3,-3) + window partition -> xw bf16 ----------------
__global__ void k_ln1(const float* __restrict__ x, const float* __restrict__ g,
                      const float* __restrict__ b, u16* __restrict__ xw, int t0) {
  int wid = threadIdx.x >> 6, lane = threadIdx.x & 63;
  int t = t0 + blockIdx.x * 4 + wid;          // global window-row index
  int bi = t / 3136, rem = t % 3136;
  int win = rem / NTOK, n = rem % NTOK;
  int wh = win >> 3, ww = win & 7, ii = n / 7, jj = n % 7;
  int h = (wh * 7 + ii + 3) % 56;
  int w = (ww * 7 + jj + 3) % 56;
  const float* src = x + ((size_t)bi * TOKENS + 1 + h * 56 + w) * DIM;
  float v[6];
  #pragma unroll
  for (int e = 0; e < 6; e++) v[e] = src[lane + e * 64];
  float s = v[0] + v[1] + v[2] + v[3] + v[4] + v[5];
  #pragma unroll
  for (int m = 1; m < 64; m <<= 1) s += __shfl_xor(s, m);
  float mu = s * (1.0f / 384.0f);
  float q = 0.f;
  #pragma unroll
  for (int e = 0; e < 6; e++) { float d = v[e] - mu; q += d * d; }
  #pragma unroll
  for (int m = 1; m < 64; m <<= 1) q += __shfl_xor(q, m);
  float rstd = rsqrtf(q * (1.0f / 384.0f) + 1e-5f);
  u16* dst = xw + (size_t)(t - t0) * DIM;
  #pragma unroll
  for (int e = 0; e < 6; e++) {
    int c = lane + e * 64;
    dst[c] = f2b((v[e] - mu) * rstd * g[c] + b[c]);
  }
}

// ---------------- panel GEMM v2: A-panel in LDS (staged once); B fragments loaded
// ---------------- per-wave straight from global (L2-hot weights) -> NO K-loop barriers.
// MODE 0 (MR=64, 4 waves): C = A*Wa^T + ba -> bf16
// MODE 1 (MR=128, 8 waves): fused MLP; out = gelu(A*W1^T+b1)*W2^T + b2 + A -> f32
template<int MODE, int MR, int NWAVE>
__global__ __launch_bounds__(NWAVE * 64, MODE == 0 ? 3 : 2) void k_panel(
    const u16* __restrict__ A, const u16* __restrict__ Wa, const u16* __restrict__ Wb,
    const float* __restrict__ ba, const float* __restrict__ bb,
    u16* __restrict__ outb, float* __restrict__ outf, int N) {
  __shared__ __align__(16) u16 Xs[MR * 384];                    // XOR-swizzled 16B slots
  __shared__ __align__(16) u16 Hs[(MODE == 1) ? MR * 128 : 16];
  int tid = threadIdx.x;
  int wid = tid >> 6, lane = tid & 63, lo = lane & 15, hi = lane >> 4;
  int mh = (MR == 128) ? (wid >> 2) * 64 : 0;   // wave m-base
  int nq = (MR == 128 ? (wid & 3) : wid) * 32;  // wave n-base within 128-chunk
  int m0 = blockIdx.x * MR;
  const u16* Ap = A + (size_t)m0 * 384;

  // ---- stage full A-panel: contiguous stream, source pre-swizzled (rule #21) ----
  #pragma unroll
  for (int i = 0; i < 12; i++) {
    int base = (wid * 12 + i) * 1024;           // phys byte base (wave-uniform)
    int f = base + lane * 16;
    int row = f / 768;
    int slot = (f - row * 768) >> 4;            // phys 16B slot (0..47)
    gload16(Ap + row * 384 + ((slot ^ (row & 7)) << 3), (char*)Xs + base);
  }
  asm volatile("s_waitcnt vmcnt(0)" ::: "memory");
  __syncthreads();

  auto ldsA = [&](int m, int s) -> s8v {        // row m, logical 16B slot s
    return *(const s8v*)(Xs + m * 384 + ((s ^ (m & 7)) << 3));
  };

  if (MODE == 0) {
    int nch = N >> 7;
    for (int ch = 0; ch < nch; ch++) {
      const u16* W0 = Wa + (size_t)(ch * 128 + nq + lo) * 384;
      const u16* W1 = Wa + (size_t)(ch * 128 + nq + 16 + lo) * 384;
      f4v acc[4][2];
      #pragma unroll
      for (int mi = 0; mi < 4; mi++)
        #pragma unroll
        for (int ni = 0; ni < 2; ni++) acc[mi][ni] = (f4v)(0.0f);
      #pragma unroll
      for (int kt = 0; kt < 12; kt++) {
        s8v b0 = *(const s8v*)(W0 + kt * 32 + hi * 8);
        s8v b1 = *(const s8v*)(W1 + kt * 32 + hi * 8);
        s8v a[4];
        #pragma unroll
        for (int mi = 0; mi < 4; mi++) a[mi] = ldsA(mi * 16 + lo, kt * 4 + hi);
        #pragma unroll
        for (int mi = 0; mi < 4; mi++) {
          acc[mi][0] = __builtin_amdgcn_mfma_f32_16x16x32_bf16(a[mi], b0, acc[mi][0], 0, 0, 0);
          acc[mi][1] = __builtin_amdgcn_mfma_f32_16x16x32_bf16(a[mi], b1, acc[mi][1], 0, 0, 0);
        }
      }
      #pragma unroll
      for (int mi = 0; mi < 4; mi++)
        #pragma unroll
        for (int ni = 0; ni < 2; ni++) {
          int gcol = ch * 128 + nq + ni * 16 + lo;
          float bv = ba[gcol];
          #pragma unroll
          for (int r = 0; r < 4; r++) {
            int grow = mi * 16 + hi * 4 + r;
            outb[(size_t)(m0 + grow) * N + gcol] = f2b(acc[mi][ni][r] + bv);
          }
        }
    }
  } else {
    f4v acc2[3][4][2];
    #pragma unroll
    for (int g = 0; g < 3; g++)
      #pragma unroll
      for (int mi = 0; mi < 4; mi++)
        #pragma unroll
        for (int ni = 0; ni < 2; ni++) acc2[g][mi][ni] = (f4v)(0.0f);
    for (int ch = 0; ch < 12; ch++) {
      // ---- stage-1: acc1 = A * W1[128 cols]^T  (no barriers, reg-B) ----
      const u16* W0 = Wa + (size_t)(ch * 128 + nq + lo) * 384;
      const u16* W1 = Wa + (size_t)(ch * 128 + nq + 16 + lo) * 384;
      f4v acc1[4][2];
      #pragma unroll
      for (int mi = 0; mi < 4; mi++)
        #pragma unroll
        for (int ni = 0; ni < 2; ni++) acc1[mi][ni] = (f4v)(0.0f);
      #pragma unroll
      for (int kt = 0; kt < 12; kt++) {
        s8v b0 = *(const s8v*)(W0 + kt * 32 + hi * 8);
        s8v b1 = *(const s8v*)(W1 + kt * 32 + hi * 8);
        s8v a[4];
        #pragma unroll
        for (int mi = 0; mi < 4; mi++) a[mi] = ldsA(mh + mi * 16 + lo, kt * 4 + hi);
        #pragma unroll
        for (int mi = 0; mi < 4; mi++) {
          acc1[mi][0] = __builtin_amdgcn_mfma_f32_16x16x32_bf16(a[mi], b0, acc1[mi][0], 0, 0, 0);
          acc1[mi][1] = __builtin_amdgcn_mfma_f32_16x16x32_bf16(a[mi], b1, acc1[mi][1], 0, 0, 0);
        }
      }
      // ---- H = gelu(acc1 + b1) -> Hs (swizzled), two barriers around handoff ----
      __syncthreads();                 // prev chunk's Hs readers done
      #pragma unroll
      for (int mi = 0; mi < 4; mi++)
        #pragma unroll
        for (int ni = 0; ni < 2; ni++) {
          int col = nq + ni * 16 + lo;
          float bv = ba[ch * 128 + col];
          int sl = col >> 3, el = col & 7;
          #pragma unroll
          for (int r = 0; r < 4; r++) {
            int m = mh + mi * 16 + hi * 4 + r;
            Hs[m * 128 + ((sl ^ (m & 7)) << 3) + el] = f2b(gelu_f(acc1[mi][ni][r] + bv));
          }
        }
      __syncthreads();                 // Hs visible
      // ---- stage-2: acc2 += H * W2^T  (no barriers, reg-B) ----
      #pragma unroll
      for (int n2g = 0; n2g < 3; n2g++) {
        const u16* V0 = Wb + (size_t)(n2g * 128 + nq + lo) * 1536 + ch * 128;
        const u16* V1 = Wb + (size_t)(n2g * 128 + nq + 16 + lo) * 1536 + ch * 128;
        #pragma unroll
        for (int kt = 0; kt < 4; kt++) {
          s8v b0 = *(const s8v*)(V0 + kt * 32 + hi * 8);
          s8v b1 = *(const s8v*)(V1 + kt * 32 + hi * 8);
          s8v a[4];
          #pragma unroll
          for (int mi = 0; mi < 4; mi++) {
            int m = mh + mi * 16 + lo;
            int s = kt * 4 + hi;
            a[mi] = *(const s8v*)(Hs + m * 128 + ((s ^ (m & 7)) << 3));
          }
          #pragma unroll
          for (int mi = 0; mi < 4; mi++) {
            acc2[n2g][mi][0] = __builtin_amdgcn_mfma_f32_16x16x32_bf16(a[mi], b0, acc2[n2g][mi][0], 0, 0, 0);
            acc2[n2g][mi][1] = __builtin_amdgcn_mfma_f32_16x16x32_bf16(a[mi], b1, acc2[n2g][mi][1], 0, 0, 0);
          }
        }
      }
    }
    // ---- epilogue: + bias + resid(from Xs) -> f32 out, row-guarded ----
    #pragma unroll
    for (int n2g = 0; n2g < 3; n2g++)
      #pragma unroll
      for (int mi = 0; mi < 4; mi++)
        #pragma unroll
        for (int ni = 0; ni < 2; ni++) {
          int gcol = n2g * 128 + nq + ni * 16 + lo;
          float bv = bb[gcol];
          int sl = gcol >> 3, el = gcol & 7;
          #pragma unroll
          for (int r = 0; r < 4; r++) {
            int ml = mh + mi * 16 + hi * 4 + r;
            int orow = m0 + ml;
            if (orow < M_FULL) {
              float res = b2f(Xs[ml * 384 + ((sl ^ (ml & 7)) << 3) + el]);
              outf[(size_t)orow * 384 + gcol] = acc2[n2g][mi][ni][r] + bv + res;
            }
          }
        }
  }
}

// ---------------- MFMA attention: one wave per window, 12 heads serial ----------------
__global__ __launch_bounds__(256) void k_attn2(const u16* __restrict__ qkv,
                                               const float* __restrict__ ADD,
                                               u16* __restrict__ ao, int win0) {
  __shared__ u16 PT[4][64][76];   // P transposed: PT[j][i] (+12 pad: 2-way-free banks)
  __shared__ u16 VT[4][32][76];   // V transposed: VT[d][j]
  int wid = threadIdx.x >> 6, lane = threadIdx.x & 63;
  int lo = lane & 15, hi = lane >> 4;
  int win_l = blockIdx.x * 4 + wid;
  int nw = (win0 + win_l) & 63;
  int wh = nw >> 3, ww = nw & 7;
  int cls = ((wh == 7) ? 2 : 0) + ((ww == 7) ? 1 : 0);
  size_t rowbase = (size_t)win_l * NTOK;
  u16 (*pt)[76] = PT[wid];
  u16 (*vt)[76] = VT[wid];

  int rcl[4];
  #pragma unroll
  for (int ti = 0; ti < 4; ti++) {
    int r = ti * 16 + lo;
    rcl[ti] = r < NTOK ? r : NTOK - 1;      // clamped fragment row
  }
  int jrow = lane < NTOK ? lane : NTOK - 1; // clamped V row for staging

  for (int h = 0; h < HEADS; h++) {
    s8v af[4], bf[4];
    #pragma unroll
    for (int ti = 0; ti < 4; ti++) {
      af[ti] = *(const s8v*)(qkv + (rowbase + rcl[ti]) * 1152 + h * 32 + hi * 8);
      bf[ti] = *(const s8v*)(qkv + (rowbase + rcl[ti]) * 1152 + 384 + h * 32 + hi * 8);
    }
    f4v st[4][4];
    #pragma unroll
    for (int mi = 0; mi < 4; mi++)
      #pragma unroll
      for (int ni = 0; ni < 4; ni++)
        st[mi][ni] = __builtin_amdgcn_mfma_f32_16x16x32_bf16(af[mi], bf[ni], (f4v)(0.0f), 0, 0, 0);

    {
      const u16* vsrc = qkv + (rowbase + jrow) * 1152 + 768 + h * 32;
      #pragma unroll
      for (int d0 = 0; d0 < 32; d0 += 8) {
        s8v v = *(const s8v*)(vsrc + d0);
        #pragma unroll
        for (int e = 0; e < 8; e++) vt[d0 + e][lane] = (u16)v[e];
      }
    }

    const float* addb = ADD + ((size_t)cls * HEADS + h) * (NTOK * NTOK);
    #pragma unroll
    for (int mi = 0; mi < 4; mi++)
      #pragma unroll
      for (int ni = 0; ni < 4; ni++) {
        int jj = ni * 16 + lo;
        #pragma unroll
        for (int r = 0; r < 4; r++) {
          int i = mi * 16 + hi * 4 + r;
          if (jj < NTOK) {
            int ic = i < NTOK ? i : NTOK - 1;
            st[mi][ni][r] += addb[ic * NTOK + jj];
          } else st[mi][ni][r] = -1e30f;
        }
      }

    float invl[4][4];
    #pragma unroll
    for (int mi = 0; mi < 4; mi++)
      #pragma unroll
      for (int r = 0; r < 4; r++) {
        float m = fmaxf(fmaxf(st[mi][0][r], st[mi][1][r]), fmaxf(st[mi][2][r], st[mi][3][r]));
        #pragma unroll
        for (int msk = 1; msk < 16; msk <<= 1) m = fmaxf(m, __shfl_xor(m, msk));
        float s = 0.f;
        #pragma unroll
        for (int ni = 0; ni < 4; ni++) {
          float p = __expf(st[mi][ni][r] - m);
          st[mi][ni][r] = p;
          s += p;
        }
        #pragma unroll
        for (int msk = 1; msk < 16; msk <<= 1) s += __shfl_xor(s, msk);
        invl[mi][r] = 1.0f / s;
      }

    #pragma unroll
    for (int ni = 0; ni < 4; ni++)
      #pragma unroll
      for (int mi = 0; mi < 4; mi++) {
        ushort4 pk;
        pk.x = f2b(st[mi][ni][0]); pk.y = f2b(st[mi][ni][1]);
        pk.z = f2b(st[mi][ni][2]); pk.w = f2b(st[mi][ni][3]);
        *(ushort4*)(&pt[ni * 16 + lo][mi * 16 + hi * 4]) = pk;
      }

    f4v ot[4][2];
    #pragma unroll
    for (int mi = 0; mi < 4; mi++)
      #pragma unroll
      for (int dt = 0; dt < 2; dt++) ot[mi][dt] = (f4v)(0.0f);
    #pragma unroll
    for (int kt = 0; kt < 2; kt++) {
      s8v pa[4], vb[2];
      #pragma unroll
      for (int mi = 0; mi < 4; mi++) {
        s8v p;
        #pragma unroll
        for (int e = 0; e < 8; e++) p[e] = (short)pt[kt * 32 + hi * 8 + e][mi * 16 + lo];
        pa[mi] = p;
      }
      #pragma unroll
      for (int dt = 0; dt < 2; dt++) {
        short4 a = *(const short4*)(&vt[dt * 16 + lo][kt * 32 + hi * 8]);
        short4 b = *(const short4*)(&vt[dt * 16 + lo][kt * 32 + hi * 8 + 4]);
        s8v v; v[0] = a.x; v[1] = a.y; v[2] = a.z; v[3] = a.w;
               v[4] = b.x; v[5] = b.y; v[6] = b.z; v[7] = b.w;
        vb[dt] = v;
      }
      #pragma unroll
      for (int mi = 0; mi < 4; mi++)
        #pragma unroll
        for (int dt = 0; dt < 2; dt++)
          ot[mi][dt] = __builtin_amdgcn_mfma_f32_16x16x32_bf16(pa[mi], vb[dt], ot[mi][dt], 0, 0, 0);
    }

    #pragma unroll
    for (int mi = 0; mi < 4; mi++)
      #pragma unroll
      for (int r = 0; r < 4; r++) {
        int i = mi * 16 + hi * 4 + r;
        if (i < NTOK) {
          u16* op = ao + (rowbase + i) * DIM + h * 32 + lo;
          op[0]  = f2b(ot[mi][0][r] * invl[mi][r]);
          op[16] = f2b(ot[mi][1][r] * invl[mi][r]);
        }
      }
  }
}

// ---------------- un-window + roll(+3,+3) + residual + LN2 -> x2 bf16 ----------------
__global__ void k_ln2(const float* __restrict__ x, const u16* __restrict__ proj,
                      const float* __restrict__ g, const float* __restrict__ b,
                      u16* __restrict__ x2b) {
  int wid = threadIdx.x >> 6, lane = threadIdx.x & 63;
  int r = blockIdx.x * 4 + wid;
  u16* dst = x2b + (size_t)r * DIM;
  if (r >= M_FULL) {
    u16 z = f2b(0.0f);
    #pragma unroll
    for (int e = 0; e < 6; e++) dst[lane + e * 64] = z;
    return;
  }
  int bi = r / TOKENS, tk = r % TOKENS;
  const float* xs = x + (size_t)r * DIM;
  float v[6];
  if (tk == 0) {
    #pragma unroll
    for (int e = 0; e < 6; e++) v[e] = xs[lane + e * 64];
  } else {
    int p = tk - 1, hh = p / 56, wp = p % 56;
    int a = (hh + 53) % 56, bw = (wp + 53) % 56;   // inverse roll by +3
    int wh = a / 7, ii = a % 7, w2 = bw / 7, jj = bw % 7;
    size_t prow = ((size_t)bi * 64 + wh * 8 + w2) * NTOK + ii * 7 + jj;
    const u16* ps = proj + prow * DIM;
    #pragma unroll
    for (int e = 0; e < 6; e++) v[e] = xs[lane + e * 64] + b2f(ps[lane + e * 64]);
  }
  float s = v[0] + v[1] + v[2] + v[3] + v[4] + v[5];
  #pragma unroll
  for (int m = 1; m < 64; m <<= 1) s += __shfl_xor(s, m);
  float mu = s * (1.0f / 384.0f);
  float q = 0.f;
  #pragma unroll
  for (int e = 0; e < 6; e++) { float d = v[e] - mu; q += d * d; }
  #pragma unroll
  for (int m = 1; m < 64; m <<= 1) q += __shfl_xor(q, m);
  float rstd = rsqrtf(q * (1.0f / 384.0f) + 1e-5f);
  #pragma unroll
  for (int e = 0; e < 6; e++) {
    int c = lane + e * 64;
    dst[c] = f2b((v[e] - mu) * rstd * g[c] + b[c]);
  }
}

extern "C" void kernel_launch(void* const* d_in, const int* in_sizes, int n_in,
                              void* d_out, int out_size, void* d_ws, size_t ws_size,
                              hipStream_t stream) {
  const float* x      = (const float*)d_in[0];
  const float* n1g    = (const float*)d_in[1];
  const float* n1b    = (const float*)d_in[2];
  const float* qkv_w  = (const float*)d_in[3];
  const float* qkv_b  = (const float*)d_in[4];
  const float* rpb    = (const float*)d_in[5];
  const float* proj_w = (const float*)d_in[6];
  const float* proj_b = (const float*)d_in[7];
  const float* n2g    = (const float*)d_in[8];
  const float* n2b    = (const float*)d_in[9];
  const float* fc1_w  = (const float*)d_in[10];
  const float* fc1_b  = (const float*)d_in[11];
  const float* fc2_w  = (const float*)d_in[12];
  const float* fc2_b  = (const float*)d_in[13];
  float* outp = (float*)d_out;

  auto al = [](size_t v) { return (v + 255) & ~(size_t)255; };
  size_t fixed = al(884736) + al(294912) + al(1179648) + al(1179648) + al(4608)
               + al(460992) + al((size_t)M_ATTN * 768) + al((size_t)M_PAD * 768);
  const int cands[5] = {1, 2, 4, 8, 16};
  int NC1 = 16;
  for (int ci = 0; ci < 5; ci++) {
    int c1 = cands[ci];
    size_t tot = fixed + al((size_t)(M_ATTN / c1) * 768) + al((size_t)(M_ATTN / c1) * 2304);
    if (tot <= ws_size) { NC1 = c1; break; }
  }
  char* p = (char*)d_ws;
  auto take = [&](size_t bytes) { char* r = p; p += al(bytes); return r; };
  u16* wt_qkv  = (u16*)take(884736);
  u16* wt_proj = (u16*)take(294912);
  u16* wt_fc1  = (u16*)take(1179648);
  u16* wt_fc2  = (u16*)take(1179648);
  float* qkvb_s = (float*)take(4608);
  float* ADDt   = (float*)take(460992);
  u16* PROJ = (u16*)take((size_t)M_ATTN * 768);
  u16* X2B  = (u16*)take((size_t)M_PAD * 768);
  int chunkM = M_ATTN / NC1;
  u16* XW   = (u16*)take((size_t)chunkM * 768);
  u16* QKV  = (u16*)take((size_t)chunkM * 2304);
  u16* AO = XW;   // alias: XW dead after QKV GEMM

  k_convert<<<2304, 256, 0, stream>>>(qkv_w, qkv_b, proj_w, fc1_w, fc2_w,
                                      wt_qkv, qkvb_s, wt_proj, wt_fc1, wt_fc2);
  k_addtab<<<451, 256, 0, stream>>>(rpb, ADDt);
  int chunkWin = chunkM / NTOK;
  for (int c = 0; c < NC1; c++) {
    int t0 = c * chunkM;
    k_ln1<<<chunkM / 4, 256, 0, stream>>>(x, n1g, n1b, XW, t0);
    k_panel<0, 64, 4><<<chunkM / 64, 256, 0, stream>>>(XW, wt_qkv, nullptr, qkvb_s,
                                                       nullptr, QKV, nullptr, 1152);
    k_attn2<<<chunkWin / 4, 256, 0, stream>>>(QKV, ADDt, AO, c * chunkWin);
    k_panel<0, 64, 4><<<chunkM / 64, 256, 0, stream>>>(AO, wt_proj, nullptr, proj_b,
                                                       nullptr, PROJ + (size_t)t0 * DIM,
                                                       nullptr, 384);
  }
  k_ln2<<<M_PAD / 4, 256, 0, stream>>>(x, PROJ, n2g, n2b, X2B);
  k_panel<1, 128, 8><<<M_PAD / 128, 512, 0, stream>>>(X2B, wt_fc1, wt_fc2, fc1_b, fc2_b,
                                                      nullptr, outp, 384);
}

// Round 7
// 1384.162 us; speedup vs baseline: 1.1788x; 1.1788x over previous
//
#include <hip/hip_runtime.h>
#include <hip/hip_bf16.h>

#define DIM 384
#define HEADS 12
#define NTOK 49
#define TOKENS 3137
#define M_ATTN 100352   // 32*64*49 window rows
#define M_FULL 100384   // 32*3137 token rows
#define M_PAD  100480   // 785*128
#define SCALEQ 0.17677669529663687f

typedef __attribute__((ext_vector_type(8))) short s8v;
typedef __attribute__((ext_vector_type(4))) float f4v;
typedef unsigned short u16;

__device__ __forceinline__ float b2f(int s) {
  union { unsigned u; float f; } c; c.u = ((unsigned)(s & 0xffff)) << 16; return c.f;
}
__device__ __forceinline__ u16 f2b(float f) {
  __hip_bfloat16 h = __float2bfloat16(f);
  return *reinterpret_cast<u16*>(&h);
}
__device__ __forceinline__ void gload16(const void* g, void* l) {
  __builtin_amdgcn_global_load_lds((const __attribute__((address_space(1))) void*)g,
                                   (__attribute__((address_space(3))) void*)l, 16, 0, 0);
}
__device__ __forceinline__ float gelu_f(float val) {
  // gelu(x) ~= x * sigmoid(1.5957691x + 0.0713548x^3), |err|<3e-3
  float u = __builtin_fmaf(0.0713548163f * val, val * val, 1.5957691216f * val);
  return val * __builtin_amdgcn_rcpf(1.0f + __expf(-u));
}

// ---------------- weight convert: f32 -> bf16, transposed to [N][K] ----------------
__global__ void k_convert(const float* __restrict__ qkv_w, const float* __restrict__ qkv_b,
                          const float* __restrict__ proj_w, const float* __restrict__ fc1_w,
                          const float* __restrict__ fc2_w,
                          u16* __restrict__ wt_qkv, float* __restrict__ qkvb_s,
                          u16* __restrict__ wt_proj, u16* __restrict__ wt_fc1,
                          u16* __restrict__ wt_fc2) {
  int i = blockIdx.x * 256 + threadIdx.x;
  if (i < 1152 * 384) { int n = i / 384, k = i % 384;
    float v = qkv_w[(size_t)k * 1152 + n]; if (n < 384) v *= SCALEQ; wt_qkv[i] = f2b(v); }
  if (i < 1152) qkvb_s[i] = qkv_b[i] * (i < 384 ? SCALEQ : 1.0f);
  if (i < 384 * 384) { int n = i / 384, k = i % 384; wt_proj[i] = f2b(proj_w[(size_t)k * 384 + n]); }
  if (i < 1536 * 384) { int n = i / 384, k = i % 384; wt_fc1[i] = f2b(fc1_w[(size_t)k * 1536 + n]); }
  if (i < 384 * 1536) { int n = i / 1536, k = i % 1536; wt_fc2[i] = f2b(fc2_w[(size_t)k * 384 + n]); }
}

// ---------------- ADD table: bias + shift mask per window class ----------------
__global__ void k_addtab(const float* __restrict__ rpb, float* __restrict__ ADD) {
  int idx = blockIdx.x * 256 + threadIdx.x;
  if (idx >= 4 * HEADS * NTOK * NTOK) return;
  int j = idx % NTOK, t = idx / NTOK;
  int i = t % NTOK; t /= NTOK;
  int h = t % HEADS; int cls = t / HEADS;
  int ii = i / 7, jj = i % 7, ji = j / 7, j2 = j % 7;
  int rpi = (ii - ji + 6) * 13 + (jj - j2 + 6);
  float v = rpb[rpi * HEADS + h];
  int rh = (cls & 2) ? (ii < 4 ? 1 : 2) : 0;
  int rw = (cls & 1) ? (jj < 4 ? 1 : 2) : 0;
  int sh = (cls & 2) ? (ji < 4 ? 1 : 2) : 0;
  int sw = (cls & 1) ? (j2 < 4 ? 1 : 2) : 0;
  if (rh != sh || rw != sw) v -= 100.0f;
  ADD[idx] = v;
}

// ---------------- fused LN1 + roll/window + QKV GEMM ----------------
// block = 64 window-rows; LN1 staged into LDS A-panel; 9 N-chunks of 128 with
// dbuf'd weight tiles (round-4-verified counted-vmcnt pattern).
__global__ __launch_bounds__(256, 2) void k_lnqkv(
    const float* __restrict__ x, const float* __restrict__ g1, const float* __restrict__ b1,
    const u16* __restrict__ Wq, const float* __restrict__ ba,
    u16* __restrict__ QKV, int t0) {
  __shared__ __align__(16) u16 Xs[64 * 384];      // 48 KB, 48 slots/row, XOR-swz
  __shared__ __align__(16) u16 Bsb[2][128 * 64];  // 2 x 16 KB
  int tid = threadIdx.x, wid = tid >> 6, lane = tid & 63;
  int lo = lane & 15, hi = lane >> 4;
  int m0 = blockIdx.x * 64;
  // ---- LN1 staging: 4 rows/pass (16 lanes per row), 4 passes per wave ----
  int q4 = lane >> 4, l16 = lane & 15;
  #pragma unroll
  for (int pass = 0; pass < 4; pass++) {
    int ml = wid * 16 + pass * 4 + q4;
    int wr = t0 + m0 + ml;
    int bi = wr / 3136, rem = wr % 3136;
    int win = rem / NTOK, n = rem % NTOK;
    int wh = win >> 3, ww = win & 7, ii = n / 7, jj = n % 7;
    int h = (wh * 7 + ii + 3) % 56, w = (ww * 7 + jj + 3) % 56;
    const float4* src = (const float4*)(x + ((size_t)bi * TOKENS + 1 + h * 56 + w) * DIM);
    float4 v[6];
    #pragma unroll
    for (int e = 0; e < 6; e++) v[e] = src[l16 + e * 16];
    float s = 0.f, ss = 0.f;
    #pragma unroll
    for (int e = 0; e < 6; e++) {
      s += v[e].x + v[e].y + v[e].z + v[e].w;
      ss += v[e].x * v[e].x + v[e].y * v[e].y + v[e].z * v[e].z + v[e].w * v[e].w;
    }
    #pragma unroll
    for (int msk = 1; msk < 16; msk <<= 1) { s += __shfl_xor(s, msk); ss += __shfl_xor(ss, msk); }
    float mu = s * (1.0f / 384.0f);
    float rstd = rsqrtf(ss * (1.0f / 384.0f) - mu * mu + 1e-5f);
    #pragma unroll
    for (int e = 0; e < 6; e++) {
      int c0 = e * 64 + l16 * 4;
      ushort4 pk;
      pk.x = f2b((v[e].x - mu) * rstd * g1[c0] + b1[c0]);
      pk.y = f2b((v[e].y - mu) * rstd * g1[c0 + 1] + b1[c0 + 1]);
      pk.z = f2b((v[e].z - mu) * rstd * g1[c0 + 2] + b1[c0 + 2]);
      pk.w = f2b((v[e].w - mu) * rstd * g1[c0 + 3] + b1[c0 + 3]);
      int slot = c0 >> 3, el = c0 & 7;
      *(ushort4*)(&Xs[ml * 384 + ((slot ^ (ml & 7)) << 3) + el]) = pk;
    }
  }
  __syncthreads();
  // ---- GEMM: 9 N-chunks; weight tiles [128n x 64k] dbuf'd ----
  int rl = lane >> 3, sl = (lane & 7) ^ rl;     // pre-swizzled stage source
  for (int ch = 0; ch < 9; ch++) {
    const u16* Bg = Wq + (size_t)(ch * 128 + wid * 32 + rl) * 384 + sl * 8;
    u16* Bl0 = Bsb[0] + wid * 32 * 64;
    u16* Bl1 = Bsb[1] + wid * 32 * 64;
    auto stb = [&](int bf, int ks) {
      u16* dst = bf ? Bl1 : Bl0;
      #pragma unroll
      for (int g_ = 0; g_ < 4; g_++)
        gload16(Bg + (size_t)(g_ * 8) * 384 + ks * 64, dst + g_ * 8 * 64);
    };
    f4v acc[4][2];
    #pragma unroll
    for (int mi = 0; mi < 4; mi++)
      #pragma unroll
      for (int ni = 0; ni < 2; ni++) acc[mi][ni] = (f4v)(0.0f);
    stb(0, 0);
    for (int ks = 0; ks < 6; ks++) {
      int c = ks & 1;
      if (ks + 1 < 6) {
        stb(1 - c, ks + 1);
        asm volatile("s_waitcnt vmcnt(4)" ::: "memory");
      } else {
        asm volatile("s_waitcnt vmcnt(0)" ::: "memory");
      }
      __builtin_amdgcn_s_barrier();
      __builtin_amdgcn_sched_barrier(0);
      s8v a[2][4], bf_[2][2];
      const u16* Bcur = Bsb[c];
      #pragma unroll
      for (int kk = 0; kk < 2; kk++) {
        #pragma unroll
        for (int mi = 0; mi < 4; mi++) {
          int row = mi * 16 + lo;
          int s2 = ks * 8 + kk * 4 + hi;
          a[kk][mi] = *(const s8v*)(Xs + row * 384 + ((s2 ^ (row & 7)) << 3));
        }
        #pragma unroll
        for (int ni = 0; ni < 2; ni++) {
          int row = wid * 32 + ni * 16 + lo;
          bf_[kk][ni] = *(const s8v*)(Bcur + row * 64 + (((kk * 4 + hi) ^ (row & 7)) << 3));
        }
      }
      asm volatile("s_waitcnt lgkmcnt(0)" ::: "memory");
      __builtin_amdgcn_sched_barrier(0);
      __builtin_amdgcn_s_barrier();
      __builtin_amdgcn_sched_barrier(0);
      __builtin_amdgcn_s_setprio(1);
      #pragma unroll
      for (int kk = 0; kk < 2; kk++)
        #pragma unroll
        for (int mi = 0; mi < 4; mi++)
          #pragma unroll
          for (int ni = 0; ni < 2; ni++)
            acc[mi][ni] = __builtin_amdgcn_mfma_f32_16x16x32_bf16(a[kk][mi], bf_[kk][ni], acc[mi][ni], 0, 0, 0);
      __builtin_amdgcn_s_setprio(0);
    }
    // epilogue: bias + store bf16
    #pragma unroll
    for (int mi = 0; mi < 4; mi++)
      #pragma unroll
      for (int ni = 0; ni < 2; ni++) {
        int gcol = ch * 128 + wid * 32 + ni * 16 + lo;
        float bv = ba[gcol];
        #pragma unroll
        for (int r = 0; r < 4; r++) {
          int row = m0 + mi * 16 + hi * 4 + r;
          QKV[(size_t)row * 1152 + gcol] = f2b(acc[mi][ni][r] + bv);
        }
      }
  }
}

// ---------------- fused proj + un-window/roll + residual + LN2 -> X2B bf16 ----------------
// block = 64 window-rows x full N=384; single-buffered weight tiles (24 KB LDS).
__global__ __launch_bounds__(256, 3) void k_projln(
    const u16* __restrict__ AO, const u16* __restrict__ Wp, const float* __restrict__ pb,
    const float* __restrict__ x, const float* __restrict__ g2, const float* __restrict__ b2,
    u16* __restrict__ X2B, int t0) {
  __shared__ __align__(16) u16 Bs[384 * 32];   // 24 KB, 4 slots/row, XOR-swz (&3)
  __shared__ float part[4][64][2];
  int tid = threadIdx.x, wid = tid >> 6, lane = tid & 63;
  int lo = lane & 15, hi = lane >> 4;
  int nq2 = wid * 96;
  int m0 = blockIdx.x * 64;
  int rl2 = lane >> 2, sl2 = (lane & 3) ^ (rl2 & 3);
  f4v acc[4][6];
  #pragma unroll
  for (int mi = 0; mi < 4; mi++)
    #pragma unroll
    for (int ni = 0; ni < 6; ni++) acc[mi][ni] = (f4v)(0.0f);
  for (int kt = 0; kt < 12; kt++) {
    s8v a[4];
    #pragma unroll
    for (int mi = 0; mi < 4; mi++)
      a[mi] = *(const s8v*)(AO + (size_t)(m0 + mi * 16 + lo) * 384 + kt * 32 + hi * 8);
    __syncthreads();                 // prev tile readers done
    #pragma unroll
    for (int i = 0; i < 6; i++) {
      int gi = wid * 6 + i;
      gload16(Wp + (size_t)(gi * 16 + rl2) * 384 + kt * 32 + sl2 * 8, (char*)Bs + gi * 1024);
    }
    asm volatile("s_waitcnt vmcnt(0)" ::: "memory");
    __syncthreads();                 // tile visible
    s8v b[6];
    #pragma unroll
    for (int ni = 0; ni < 6; ni++) {
      int row = nq2 + ni * 16 + lo;
      b[ni] = *(const s8v*)(Bs + row * 32 + ((hi ^ (row & 3)) << 3));
    }
    #pragma unroll
    for (int mi = 0; mi < 4; mi++)
      #pragma unroll
      for (int ni = 0; ni < 6; ni++)
        acc[mi][ni] = __builtin_amdgcn_mfma_f32_16x16x32_bf16(a[mi], b[ni], acc[mi][ni], 0, 0, 0);
  }
  // ---- epilogue: + bias + x residual, per-row LN2, write X2B at token rows ----
  float pbv[6], gv[6], bv[6];
  #pragma unroll
  for (int ni = 0; ni < 6; ni++) {
    int gcol = nq2 + ni * 16 + lo;
    pbv[ni] = pb[gcol]; gv[ni] = g2[gcol]; bv[ni] = b2[gcol];
  }
  #pragma unroll
  for (int mi = 0; mi < 4; mi++)
    #pragma unroll
    for (int r = 0; r < 4; r++) {
      int wr = t0 + m0 + mi * 16 + hi * 4 + r;
      int bi = wr / 3136, rem = wr % 3136;
      int win = rem / NTOK, n = rem % NTOK;
      int wh = win >> 3, ww = win & 7, ii = n / 7, jj = n % 7;
      int h = (wh * 7 + ii + 3) % 56, w = (ww * 7 + jj + 3) % 56;
      int tok = bi * TOKENS + 1 + h * 56 + w;
      const float* xp = x + (size_t)tok * DIM;
      float s = 0.f, ss = 0.f;
      #pragma unroll
      for (int ni = 0; ni < 6; ni++) {
        float v = acc[mi][ni][r] + pbv[ni] + xp[nq2 + ni * 16 + lo];
        acc[mi][ni][r] = v;
        s += v; ss += v * v;
      }
      #pragma unroll
      for (int msk = 1; msk < 16; msk <<= 1) { s += __shfl_xor(s, msk); ss += __shfl_xor(ss, msk); }
      part[wid][mi * 16 + hi * 4 + r][0] = s;
      part[wid][mi * 16 + hi * 4 + r][1] = ss;
    }
  __syncthreads();
  #pragma unroll
  for (int mi = 0; mi < 4; mi++)
    #pragma unroll
    for (int r = 0; r < 4; r++) {
      int wr = t0 + m0 + mi * 16 + hi * 4 + r;
      int bi = wr / 3136, rem = wr % 3136;
      int win = rem / NTOK, n = rem % NTOK;
      int wh = win >> 3, ww = win & 7, ii = n / 7, jj = n % 7;
      int h = (wh * 7 + ii + 3) % 56, w = (ww * 7 + jj + 3) % 56;
      int tok = bi * TOKENS + 1 + h * 56 + w;
      int rloc = mi * 16 + hi * 4 + r;
      float S = part[0][rloc][0] + part[1][rloc][0] + part[2][rloc][0] + part[3][rloc][0];
      float SS = part[0][rloc][1] + part[1][rloc][1] + part[2][rloc][1] + part[3][rloc][1];
      float mu = S * (1.0f / 384.0f);
      float rstd = rsqrtf(SS * (1.0f / 384.0f) - mu * mu + 1e-5f);
      u16* op = X2B + (size_t)tok * DIM;
      #pragma unroll
      for (int ni = 0; ni < 6; ni++)
        op[nq2 + ni * 16 + lo] = f2b((acc[mi][ni][r] - mu) * rstd * gv[ni] + bv[ni]);
    }
}

// ---------------- time-token LN2 + pad-row zero fill for X2B ----------------
__global__ void k_tt(const float* __restrict__ x, const float* __restrict__ g2,
                     const float* __restrict__ b2, u16* __restrict__ X2B) {
  int wid = threadIdx.x >> 6, lane = threadIdx.x & 63;
  int idx = blockIdx.x * 4 + wid;
  if (idx >= 128) return;
  if (idx < 32) {
    size_t row = (size_t)idx * TOKENS;
    const float* xs = x + row * DIM;
    float v[6];
    #pragma unroll
    for (int e = 0; e < 6; e++) v[e] = xs[lane + e * 64];
    float s = 0.f, ss = 0.f;
    #pragma unroll
    for (int e = 0; e < 6; e++) { s += v[e]; ss += v[e] * v[e]; }
    #pragma unroll
    for (int m = 1; m < 64; m <<= 1) { s += __shfl_xor(s, m); ss += __shfl_xor(ss, m); }
    float mu = s * (1.0f / 384.0f);
    float rstd = rsqrtf(ss * (1.0f / 384.0f) - mu * mu + 1e-5f);
    u16* dst = X2B + row * DIM;
    #pragma unroll
    for (int e = 0; e < 6; e++) {
      int c = lane + e * 64;
      dst[c] = f2b((v[e] - mu) * rstd * g2[c] + b2[c]);
    }
  } else {
    size_t row = (size_t)M_FULL + (idx - 32);
    u16* dst = X2B + row * DIM;
    u16 z = f2b(0.0f);
    #pragma unroll
    for (int e = 0; e < 6; e++) dst[lane + e * 64] = z;
  }
}

// ---------------- bf16 MFMA GEMM (round-4 verified): dbuf + counted vmcnt + T1 remap.
// MODE 1: bias+gelu->bf16, 2: bias + resid -> f32 d_out w/ row guard
template<int MODE>
__global__ __launch_bounds__(256) void k_gemm(
    const u16* __restrict__ A, const u16* __restrict__ Bt,
    const float* __restrict__ bias, u16* __restrict__ Cb,
    float* __restrict__ outp, const u16* __restrict__ resid,
    int N, int K, int row_off) {
  __shared__ __align__(16) u16 As[2][128 * 64];
  __shared__ __align__(16) u16 Bs[2][128 * 64];
  int gx = gridDim.x;
  int lid = blockIdx.y * gx + blockIdx.x;
  int nwg = gx * gridDim.y;
  int q = nwg >> 3, r = nwg & 7;
  int xcd = lid & 7, loc = lid >> 3;
  int tile = (xcd < r ? xcd * (q + 1) : r * (q + 1) + (xcd - r) * q) + loc;
  int m0 = (tile / gx) * 128, n0 = (tile % gx) * 128;
  int t = threadIdx.x;
  int lane = t & 63, wave = t >> 6;
  int lo = lane & 15, hi = lane >> 4;
  int wr = (wave >> 1) * 64, wc = (wave & 1) * 64;
  int rl = lane >> 3;
  int sl = (lane & 7) ^ rl;
  const u16* Ag = A + (size_t)(m0 + wave * 32 + rl) * K + sl * 8;
  const u16* Bg = Bt + (size_t)(n0 + wave * 32 + rl) * K + sl * 8;
  f4v acc[4][4];
  #pragma unroll
  for (int m = 0; m < 4; m++)
    #pragma unroll
    for (int n = 0; n < 4; n++) acc[m][n] = (f4v)(0.0f);
  int nt = K >> 6;
#define STAGE(buf, kt) do {                                              \
    u16* al_ = As[buf] + wave * 32 * 64;                                 \
    u16* bl_ = Bs[buf] + wave * 32 * 64;                                 \
    _Pragma("unroll")                                                    \
    for (int g_ = 0; g_ < 4; g_++) {                                     \
      gload16(Ag + (size_t)(g_ * 8) * K + (kt), al_ + g_ * 8 * 64);      \
      gload16(Bg + (size_t)(g_ * 8) * K + (kt), bl_ + g_ * 8 * 64);      \
    } } while (0)
  STAGE(0, 0);
  for (int kt = 0; kt < nt; ++kt) {
    int c = kt & 1;
    if (kt + 1 < nt) {
      STAGE(1 - c, (kt + 1) << 6);
      asm volatile("s_waitcnt vmcnt(8)" ::: "memory");
    } else {
      asm volatile("s_waitcnt vmcnt(0)" ::: "memory");
    }
    __builtin_amdgcn_s_barrier();
    __builtin_amdgcn_sched_barrier(0);
    s8v af[2][4], bfr[2][4];
    #pragma unroll
    for (int kk = 0; kk < 2; kk++) {
      #pragma unroll
      for (int m = 0; m < 4; m++) {
        int row = wr + m * 16 + lo;
        af[kk][m] = *(const s8v*)(As[c] + row * 64 + (((kk * 4 + hi) ^ (row & 7)) * 8));
      }
      #pragma unroll
      for (int n = 0; n < 4; n++) {
        int row = wc + n * 16 + lo;
        bfr[kk][n] = *(const s8v*)(Bs[c] + row * 64 + (((kk * 4 + hi) ^ (row & 7)) * 8));
      }
    }
    asm volatile("s_waitcnt lgkmcnt(0)" ::: "memory");
    __builtin_amdgcn_sched_barrier(0);
    __builtin_amdgcn_s_barrier();
    __builtin_amdgcn_sched_barrier(0);
    __builtin_amdgcn_s_setprio(1);
    #pragma unroll
    for (int kk = 0; kk < 2; kk++)
      #pragma unroll
      for (int m = 0; m < 4; m++)
        #pragma unroll
        for (int n = 0; n < 4; n++)
          acc[m][n] = __builtin_amdgcn_mfma_f32_16x16x32_bf16(af[kk][m], bfr[kk][n], acc[m][n], 0, 0, 0);
    __builtin_amdgcn_s_setprio(0);
  }
#undef STAGE
  #pragma unroll
  for (int m = 0; m < 4; m++) {
    int grow = m0 + wr + m * 16 + hi * 4;
    #pragma unroll
    for (int n = 0; n < 4; n++) {
      int gcol = n0 + wc + n * 16 + lo;
      float bv = bias[gcol];
      #pragma unroll
      for (int r2 = 0; r2 < 4; r2++) {
        float val = acc[m][n][r2] + bv;
        size_t idx = (size_t)(grow + r2) * N + gcol;
        if (MODE == 1) {
          Cb[idx] = f2b(gelu_f(val));
        } else {
          int orow = grow + r2 + row_off;
          if (orow < M_FULL) {
            size_t oi = (size_t)orow * DIM + gcol;
            outp[oi] = val + b2f(resid[oi]);
          }
        }
      }
    }
  }
}

// ---------------- MFMA attention: one wave per window, 12 heads serial ----------------
__global__ __launch_bounds__(256) void k_attn2(const u16* __restrict__ qkv,
                                               const float* __restrict__ ADD,
                                               u16* __restrict__ ao, int win0) {
  __shared__ u16 PT[4][64][76];
  __shared__ u16 VT[4][32][76];
  int wid = threadIdx.x >> 6, lane = threadIdx.x & 63;
  int lo = lane & 15, hi = lane >> 4;
  int win_l = blockIdx.x * 4 + wid;
  int nw = (win0 + win_l) & 63;
  int wh = nw >> 3, ww = nw & 7;
  int cls = ((wh == 7) ? 2 : 0) + ((ww == 7) ? 1 : 0);
  size_t rowbase = (size_t)win_l * NTOK;
  u16 (*pt)[76] = PT[wid];
  u16 (*vt)[76] = VT[wid];

  int rcl[4];
  #pragma unroll
  for (int ti = 0; ti < 4; ti++) {
    int r = ti * 16 + lo;
    rcl[ti] = r < NTOK ? r : NTOK - 1;
  }
  int jrow = lane < NTOK ? lane : NTOK - 1;

  for (int h = 0; h < HEADS; h++) {
    s8v af[4], bf[4];
    #pragma unroll
    for (int ti = 0; ti < 4; ti++) {
      af[ti] = *(const s8v*)(qkv + (rowbase + rcl[ti]) * 1152 + h * 32 + hi * 8);
      bf[ti] = *(const s8v*)(qkv + (rowbase + rcl[ti]) * 1152 + 384 + h * 32 + hi * 8);
    }
    f4v st[4][4];
    #pragma unroll
    for (int mi = 0; mi < 4; mi++)
      #pragma unroll
      for (int ni = 0; ni < 4; ni++)
        st[mi][ni] = __builtin_amdgcn_mfma_f32_16x16x32_bf16(af[mi], bf[ni], (f4v)(0.0f), 0, 0, 0);

    {
      const u16* vsrc = qkv + (rowbase + jrow) * 1152 + 768 + h * 32;
      #pragma unroll
      for (int d0 = 0; d0 < 32; d0 += 8) {
        s8v v = *(const s8v*)(vsrc + d0);
        #pragma unroll
        for (int e = 0; e < 8; e++) vt[d0 + e][lane] = (u16)v[e];
      }
    }

    const float* addb = ADD + ((size_t)cls * HEADS + h) * (NTOK * NTOK);
    #pragma unroll
    for (int mi = 0; mi < 4; mi++)
      #pragma unroll
      for (int ni = 0; ni < 4; ni++) {
        int jj = ni * 16 + lo;
        #pragma unroll
        for (int r = 0; r < 4; r++) {
          int i = mi * 16 + hi * 4 + r;
          if (jj < NTOK) {
            int ic = i < NTOK ? i : NTOK - 1;
            st[mi][ni][r] += addb[ic * NTOK + jj];
          } else st[mi][ni][r] = -1e30f;
        }
      }

    float invl[4][4];
    #pragma unroll
    for (int mi = 0; mi < 4; mi++)
      #pragma unroll
      for (int r = 0; r < 4; r++) {
        float m = fmaxf(fmaxf(st[mi][0][r], st[mi][1][r]), fmaxf(st[mi][2][r], st[mi][3][r]));
        #pragma unroll
        for (int msk = 1; msk < 16; msk <<= 1) m = fmaxf(m, __shfl_xor(m, msk));
        float s = 0.f;
        #pragma unroll
        for (int ni = 0; ni < 4; ni++) {
          float p = __expf(st[mi][ni][r] - m);
          st[mi][ni][r] = p;
          s += p;
        }
        #pragma unroll
        for (int msk = 1; msk < 16; msk <<= 1) s += __shfl_xor(s, msk);
        invl[mi][r] = 1.0f / s;
      }

    #pragma unroll
    for (int ni = 0; ni < 4; ni++)
      #pragma unroll
      for (int mi = 0; mi < 4; mi++) {
        ushort4 pk;
        pk.x = f2b(st[mi][ni][0]); pk.y = f2b(st[mi][ni][1]);
        pk.z = f2b(st[mi][ni][2]); pk.w = f2b(st[mi][ni][3]);
        *(ushort4*)(&pt[ni * 16 + lo][mi * 16 + hi * 4]) = pk;
      }

    f4v ot[4][2];
    #pragma unroll
    for (int mi = 0; mi < 4; mi++)
      #pragma unroll
      for (int dt = 0; dt < 2; dt++) ot[mi][dt] = (f4v)(0.0f);
    #pragma unroll
    for (int kt = 0; kt < 2; kt++) {
      s8v pa[4], vb[2];
      #pragma unroll
      for (int mi = 0; mi < 4; mi++) {
        s8v p;
        #pragma unroll
        for (int e = 0; e < 8; e++) p[e] = (short)pt[kt * 32 + hi * 8 + e][mi * 16 + lo];
        pa[mi] = p;
      }
      #pragma unroll
      for (int dt = 0; dt < 2; dt++) {
        short4 a = *(const short4*)(&vt[dt * 16 + lo][kt * 32 + hi * 8]);
        short4 b = *(const short4*)(&vt[dt * 16 + lo][kt * 32 + hi * 8 + 4]);
        s8v v; v[0] = a.x; v[1] = a.y; v[2] = a.z; v[3] = a.w;
               v[4] = b.x; v[5] = b.y; v[6] = b.z; v[7] = b.w;
        vb[dt] = v;
      }
      #pragma unroll
      for (int mi = 0; mi < 4; mi++)
        #pragma unroll
        for (int dt = 0; dt < 2; dt++)
          ot[mi][dt] = __builtin_amdgcn_mfma_f32_16x16x32_bf16(pa[mi], vb[dt], ot[mi][dt], 0, 0, 0);
    }

    #pragma unroll
    for (int mi = 0; mi < 4; mi++)
      #pragma unroll
      for (int r = 0; r < 4; r++) {
        int i = mi * 16 + hi * 4 + r;
        if (i < NTOK) {
          u16* op = ao + (rowbase + i) * DIM + h * 32 + lo;
          op[0]  = f2b(ot[mi][0][r] * invl[mi][r]);
          op[16] = f2b(ot[mi][1][r] * invl[mi][r]);
        }
      }
  }
}

extern "C" void kernel_launch(void* const* d_in, const int* in_sizes, int n_in,
                              void* d_out, int out_size, void* d_ws, size_t ws_size,
                              hipStream_t stream) {
  const float* x      = (const float*)d_in[0];
  const float* n1g    = (const float*)d_in[1];
  const float* n1b    = (const float*)d_in[2];
  const float* qkv_w  = (const float*)d_in[3];
  const float* qkv_b  = (const float*)d_in[4];
  const float* rpb    = (const float*)d_in[5];
  const float* proj_w = (const float*)d_in[6];
  const float* proj_b = (const float*)d_in[7];
  const float* n2g    = (const float*)d_in[8];
  const float* n2b    = (const float*)d_in[9];
  const float* fc1_w  = (const float*)d_in[10];
  const float* fc1_b  = (const float*)d_in[11];
  const float* fc2_w  = (const float*)d_in[12];
  const float* fc2_b  = (const float*)d_in[13];
  float* outp = (float*)d_out;

  auto al = [](size_t v) { return (v + 255) & ~(size_t)255; };
  size_t fixed = al(884736) + al(294912) + al(1179648) + al(1179648) + al(4608)
               + al(460992) + al((size_t)M_PAD * 768);
  const int cands[3][2] = {{4, 4}, {8, 8}, {16, 16}};
  int NC1 = 16, NC2 = 16;
  for (int ci = 0; ci < 3; ci++) {
    int c1 = cands[ci][0], c2 = cands[ci][1];
    int cbb = (785 + c2 - 1) / c2;
    size_t tot = fixed + al((size_t)(M_ATTN / c1) * 2304) + al((size_t)(M_ATTN / c1) * 768)
               + al((size_t)cbb * 128 * 1536 * 2);
    if (tot <= ws_size) { NC1 = c1; NC2 = c2; break; }
  }
  char* p = (char*)d_ws;
  auto take = [&](size_t bytes) { char* r = p; p += al(bytes); return r; };
  u16* wt_qkv  = (u16*)take(884736);
  u16* wt_proj = (u16*)take(294912);
  u16* wt_fc1  = (u16*)take(1179648);
  u16* wt_fc2  = (u16*)take(1179648);
  float* qkvb_s = (float*)take(4608);
  float* ADDt   = (float*)take(460992);
  u16* X2B  = (u16*)take((size_t)M_PAD * 768);
  int chunkM = M_ATTN / NC1;
  u16* QKV  = (u16*)take((size_t)chunkM * 2304);
  u16* AO   = (u16*)take((size_t)chunkM * 768);
  int cb = (785 + NC2 - 1) / NC2;
  u16* FC1  = (u16*)take((size_t)cb * 128 * 1536 * 2);

  k_convert<<<2304, 256, 0, stream>>>(qkv_w, qkv_b, proj_w, fc1_w, fc2_w,
                                      wt_qkv, qkvb_s, wt_proj, wt_fc1, wt_fc2);
  k_addtab<<<451, 256, 0, stream>>>(rpb, ADDt);
  k_tt<<<32, 256, 0, stream>>>(x, n2g, n2b, X2B);
  int chunkWin = chunkM / NTOK;
  for (int c = 0; c < NC1; c++) {
    int t0 = c * chunkM;
    k_lnqkv<<<chunkM / 64, 256, 0, stream>>>(x, n1g, n1b, wt_qkv, qkvb_s, QKV, t0);
    k_attn2<<<chunkWin / 4, 256, 0, stream>>>(QKV, ADDt, AO, c * chunkWin);
    k_projln<<<chunkM / 64, 256, 0, stream>>>(AO, wt_proj, proj_b, x, n2g, n2b, X2B, t0);
  }
  for (int c = 0; c < NC2; c++) {
    int rb0 = c * cb;
    int nb = 785 - rb0; if (nb > cb) nb = cb; if (nb <= 0) break;
    k_gemm<1><<<dim3(12, nb), 256, 0, stream>>>(X2B + (size_t)rb0 * 128 * DIM, wt_fc1,
                                                fc1_b, FC1, nullptr, nullptr, 1536, 384, 0);
    k_gemm<2><<<dim3(3, nb), 256, 0, stream>>>(FC1, wt_fc2, fc2_b, nullptr, outp, X2B,
                                               384, 1536, rb0 * 128);
  }
}

// Round 8
// 1047.883 us; speedup vs baseline: 1.5571x; 1.3209x over previous
//
#include <hip/hip_runtime.h>
#include <hip/hip_bf16.h>

#define DIM 384
#define HEADS 12
#define NTOK 49
#define TOKENS 3137
#define M_ATTN 100352   // 32*64*49 window rows
#define M_FULL 100384   // 32*3137 token rows
#define M_PAD  100480   // 785*128
#define SCALEQ 0.17677669529663687f

typedef __attribute__((ext_vector_type(8))) short s8v;
typedef __attribute__((ext_vector_type(4))) float f4v;
typedef unsigned short u16;

__device__ __forceinline__ float b2f(int s) {
  union { unsigned u; float f; } c; c.u = ((unsigned)(s & 0xffff)) << 16; return c.f;
}
__device__ __forceinline__ u16 f2b(float f) {
  __hip_bfloat16 h = __float2bfloat16(f);
  return *reinterpret_cast<u16*>(&h);
}
__device__ __forceinline__ void gload16(const void* g, void* l) {
  __builtin_amdgcn_global_load_lds((const __attribute__((address_space(1))) void*)g,
                                   (__attribute__((address_space(3))) void*)l, 16, 0, 0);
}
__device__ __forceinline__ float gelu_f(float val) {
  float u = __builtin_fmaf(0.0713548163f * val, val * val, 1.5957691216f * val);
  return val * __builtin_amdgcn_rcpf(1.0f + __expf(-u));
}
// tiled+pre-swizzled layout [tile][ks][128 rows][64 cols]: element (row rl, col c)
// of tile lives at physical 16B-slot ((c>>3)&7) ^ (rl&7). Index in u16 units.
__device__ __forceinline__ size_t tidx(int tile, int KS, int rl, int c) {
  return ((size_t)(tile * KS + (c >> 6)) * 128 + rl) * 64
       + (((((c >> 3) & 7)) ^ (rl & 7)) << 3) + (c & 7);
}

// ---------------- weight convert: f32 -> bf16, tiled+swizzled [N/128][K/64][128][64] ----
__global__ void k_convert(const float* __restrict__ qkv_w, const float* __restrict__ qkv_b,
                          const float* __restrict__ proj_w, const float* __restrict__ fc1_w,
                          const float* __restrict__ fc2_w,
                          u16* __restrict__ wt_qkv, float* __restrict__ qkvb_s,
                          u16* __restrict__ wt_proj, u16* __restrict__ wt_fc1,
                          u16* __restrict__ wt_fc2) {
  int i = blockIdx.x * 256 + threadIdx.x;
  if (i < 1152 * 384) { int n = i / 384, k = i % 384;
    float v = qkv_w[(size_t)k * 1152 + n]; if (n < 384) v *= SCALEQ;
    wt_qkv[tidx(n >> 7, 6, n & 127, k)] = f2b(v); }
  if (i < 1152) qkvb_s[i] = qkv_b[i] * (i < 384 ? SCALEQ : 1.0f);
  if (i < 384 * 384) { int n = i / 384, k = i % 384;
    wt_proj[tidx(n >> 7, 6, n & 127, k)] = f2b(proj_w[(size_t)k * 384 + n]); }
  if (i < 1536 * 384) { int n = i / 384, k = i % 384;
    wt_fc1[tidx(n >> 7, 6, n & 127, k)] = f2b(fc1_w[(size_t)k * 1536 + n]); }
  if (i < 384 * 1536) { int n = i / 1536, k = i % 1536;
    wt_fc2[tidx(n >> 7, 24, n & 127, k)] = f2b(fc2_w[(size_t)k * 384 + n]); }
}

// ---------------- ADD table: bias + shift mask per window class ----------------
__global__ void k_addtab(const float* __restrict__ rpb, float* __restrict__ ADD) {
  int idx = blockIdx.x * 256 + threadIdx.x;
  if (idx >= 4 * HEADS * NTOK * NTOK) return;
  int j = idx % NTOK, t = idx / NTOK;
  int i = t % NTOK; t /= NTOK;
  int h = t % HEADS; int cls = t / HEADS;
  int ii = i / 7, jj = i % 7, ji = j / 7, j2 = j % 7;
  int rpi = (ii - ji + 6) * 13 + (jj - j2 + 6);
  float v = rpb[rpi * HEADS + h];
  int rh = (cls & 2) ? (ii < 4 ? 1 : 2) : 0;
  int rw = (cls & 1) ? (jj < 4 ? 1 : 2) : 0;
  int sh = (cls & 2) ? (ji < 4 ? 1 : 2) : 0;
  int sw = (cls & 1) ? (j2 < 4 ? 1 : 2) : 0;
  if (rh != sh || rw != sw) v -= 100.0f;
  ADD[idx] = v;
}

// ---------------- LN1 + roll(-3,-3) + window partition -> XW tiled bf16 ----------------
__global__ void k_ln1(const float* __restrict__ x, const float* __restrict__ g,
                      const float* __restrict__ b, u16* __restrict__ xwt, int t0) {
  int wid = threadIdx.x >> 6, lane = threadIdx.x & 63;
  int ml = blockIdx.x * 4 + wid;              // chunk-local window-row
  int t = t0 + ml;
  int bi = t / 3136, rem = t % 3136;
  int win = rem / NTOK, n = rem % NTOK;
  int wh = win >> 3, ww = win & 7, ii = n / 7, jj = n % 7;
  int h = (wh * 7 + ii + 3) % 56;
  int w = (ww * 7 + jj + 3) % 56;
  const float* src = x + ((size_t)bi * TOKENS + 1 + h * 56 + w) * DIM;
  float v[6];
  #pragma unroll
  for (int e = 0; e < 6; e++) v[e] = src[lane + e * 64];
  float s = v[0] + v[1] + v[2] + v[3] + v[4] + v[5];
  #pragma unroll
  for (int m = 1; m < 64; m <<= 1) s += __shfl_xor(s, m);
  float mu = s * (1.0f / 384.0f);
  float q = 0.f;
  #pragma unroll
  for (int e = 0; e < 6; e++) { float d = v[e] - mu; q += d * d; }
  #pragma unroll
  for (int m = 1; m < 64; m <<= 1) q += __shfl_xor(q, m);
  float rstd = rsqrtf(q * (1.0f / 384.0f) + 1e-5f);
  int tile = ml >> 7, rl = ml & 127;
  #pragma unroll
  for (int e = 0; e < 6; e++) {
    int c = lane + e * 64;
    xwt[tidx(tile, 6, rl, c)] = f2b((v[e] - mu) * rstd * g[c] + b[c]);
  }
}

// ---------------- bf16 MFMA GEMM: tiled+pre-swizzled A and B (fully sequential staging),
// dbuf + counted vmcnt + T1 remap.  KT = K/64.
// MODE 0: bias -> bf16 normal [row][N];  MODE 1: bias+gelu -> FC1 tiled (KS=24);
// MODE 2: bias + resid(X2B tiled) -> f32 d_out w/ row guard
template<int MODE>
__global__ __launch_bounds__(256) void k_gemm(
    const u16* __restrict__ At, const u16* __restrict__ Bt,
    const float* __restrict__ bias, u16* __restrict__ Cb,
    float* __restrict__ outp, const u16* __restrict__ residt,
    int N, int KT, int row_off) {
  __shared__ __align__(16) u16 As[2][128 * 64];
  __shared__ __align__(16) u16 Bs[2][128 * 64];
  int gx = gridDim.x;
  int lid = blockIdx.y * gx + blockIdx.x;
  int nwg = gx * gridDim.y;
  int q = nwg >> 3, r = nwg & 7;
  int xcd = lid & 7, loc = lid >> 3;
  int tile = (xcd < r ? xcd * (q + 1) : r * (q + 1) + (xcd - r) * q) + loc;
  int m0 = (tile / gx) * 128, n0 = (tile % gx) * 128;
  int t = threadIdx.x;
  int lane = t & 63, wave = t >> 6;
  int lo = lane & 15, hi = lane >> 4;
  int wr = (wave >> 1) * 64, wc = (wave & 1) * 64;
  // fully sequential staging: tile chunk = 16 KB contiguous; per-wave 2 KB x 4
  const u16* Ag = At + ((size_t)(m0 >> 7) * KT) * 8192 + wave * 2048 + lane * 8;
  const u16* Bg = Bt + ((size_t)(n0 >> 7) * KT) * 8192 + wave * 2048 + lane * 8;
  f4v acc[4][4];
  #pragma unroll
  for (int m = 0; m < 4; m++)
    #pragma unroll
    for (int n = 0; n < 4; n++) acc[m][n] = (f4v)(0.0f);
#define STAGE(buf, kt) do {                                              \
    u16* al_ = As[buf] + wave * 2048;                                    \
    u16* bl_ = Bs[buf] + wave * 2048;                                    \
    _Pragma("unroll")                                                    \
    for (int g_ = 0; g_ < 4; g_++) {                                     \
      gload16(Ag + (size_t)(kt) * 8192 + g_ * 512, al_ + g_ * 512);      \
      gload16(Bg + (size_t)(kt) * 8192 + g_ * 512, bl_ + g_ * 512);      \
    } } while (0)
  STAGE(0, 0);
  for (int kt = 0; kt < KT; ++kt) {
    int c = kt & 1;
    if (kt + 1 < KT) {
      STAGE(1 - c, kt + 1);
      asm volatile("s_waitcnt vmcnt(8)" ::: "memory");
    } else {
      asm volatile("s_waitcnt vmcnt(0)" ::: "memory");
    }
    __builtin_amdgcn_s_barrier();
    __builtin_amdgcn_sched_barrier(0);
    s8v af[2][4], bfr[2][4];
    #pragma unroll
    for (int kk = 0; kk < 2; kk++) {
      #pragma unroll
      for (int m = 0; m < 4; m++) {
        int row = wr + m * 16 + lo;
        af[kk][m] = *(const s8v*)(As[c] + row * 64 + (((kk * 4 + hi) ^ (row & 7)) * 8));
      }
      #pragma unroll
      for (int n = 0; n < 4; n++) {
        int row = wc + n * 16 + lo;
        bfr[kk][n] = *(const s8v*)(Bs[c] + row * 64 + (((kk * 4 + hi) ^ (row & 7)) * 8));
      }
    }
    asm volatile("s_waitcnt lgkmcnt(0)" ::: "memory");
    __builtin_amdgcn_sched_barrier(0);
    __builtin_amdgcn_s_barrier();
    __builtin_amdgcn_sched_barrier(0);
    __builtin_amdgcn_s_setprio(1);
    #pragma unroll
    for (int kk = 0; kk < 2; kk++)
      #pragma unroll
      for (int m = 0; m < 4; m++)
        #pragma unroll
        for (int n = 0; n < 4; n++)
          acc[m][n] = __builtin_amdgcn_mfma_f32_16x16x32_bf16(af[kk][m], bfr[kk][n], acc[m][n], 0, 0, 0);
    __builtin_amdgcn_s_setprio(0);
  }
#undef STAGE
  #pragma unroll
  for (int m = 0; m < 4; m++) {
    #pragma unroll
    for (int n = 0; n < 4; n++) {
      int gcol = n0 + wc + n * 16 + lo;
      float bv = bias[gcol];
      #pragma unroll
      for (int r2 = 0; r2 < 4; r2++) {
        int lrow = wr + m * 16 + hi * 4 + r2;      // local row in 128-tile
        float val = acc[m][n][r2] + bv;
        if (MODE == 0) {
          Cb[(size_t)(m0 + lrow) * N + gcol] = f2b(val);
        } else if (MODE == 1) {
          Cb[tidx(m0 >> 7, 24, lrow, gcol)] = f2b(gelu_f(val));
        } else {
          int orow = m0 + lrow + row_off;
          if (orow < M_FULL) {
            float res = b2f(residt[tidx(orow >> 7, 6, orow & 127, gcol)]);
            outp[(size_t)orow * 384 + gcol] = val + res;
          }
        }
      }
    }
  }
}

// ---------------- MFMA attention: one wave per (window, head) ----------------
__global__ __launch_bounds__(256) void k_attn2(const u16* __restrict__ qkv,
                                               const float* __restrict__ ADD,
                                               u16* __restrict__ aot, int win0) {
  __shared__ u16 PT[4][64][76];
  __shared__ u16 VT[4][32][76];
  int wid = threadIdx.x >> 6, lane = threadIdx.x & 63;
  int lo = lane & 15, hi = lane >> 4;
  int gw = blockIdx.x * 4 + wid;
  int win_l = gw / HEADS, h = gw % HEADS;
  int nw = (win0 + win_l) & 63;
  int wh = nw >> 3, ww = nw & 7;
  int cls = ((wh == 7) ? 2 : 0) + ((ww == 7) ? 1 : 0);
  size_t rowbase = (size_t)win_l * NTOK;
  u16 (*pt)[76] = PT[wid];
  u16 (*vt)[76] = VT[wid];

  int rcl[4];
  #pragma unroll
  for (int ti = 0; ti < 4; ti++) {
    int r = ti * 16 + lo;
    rcl[ti] = r < NTOK ? r : NTOK - 1;
  }
  int jrow = lane < NTOK ? lane : NTOK - 1;

  s8v af[4], bf[4];
  #pragma unroll
  for (int ti = 0; ti < 4; ti++) {
    af[ti] = *(const s8v*)(qkv + (rowbase + rcl[ti]) * 1152 + h * 32 + hi * 8);
    bf[ti] = *(const s8v*)(qkv + (rowbase + rcl[ti]) * 1152 + 384 + h * 32 + hi * 8);
  }
  f4v st[4][4];
  #pragma unroll
  for (int mi = 0; mi < 4; mi++)
    #pragma unroll
    for (int ni = 0; ni < 4; ni++)
      st[mi][ni] = __builtin_amdgcn_mfma_f32_16x16x32_bf16(af[mi], bf[ni], (f4v)(0.0f), 0, 0, 0);

  {
    const u16* vsrc = qkv + (rowbase + jrow) * 1152 + 768 + h * 32;
    #pragma unroll
    for (int d0 = 0; d0 < 32; d0 += 8) {
      s8v v = *(const s8v*)(vsrc + d0);
      #pragma unroll
      for (int e = 0; e < 8; e++) vt[d0 + e][lane] = (u16)v[e];
    }
  }

  const float* addb = ADD + ((size_t)cls * HEADS + h) * (NTOK * NTOK);
  #pragma unroll
  for (int mi = 0; mi < 4; mi++)
    #pragma unroll
    for (int ni = 0; ni < 4; ni++) {
      int jj = ni * 16 + lo;
      #pragma unroll
      for (int r = 0; r < 4; r++) {
        int i = mi * 16 + hi * 4 + r;
        if (jj < NTOK) {
          int ic = i < NTOK ? i : NTOK - 1;
          st[mi][ni][r] += addb[ic * NTOK + jj];
        } else st[mi][ni][r] = -1e30f;
      }
    }

  float invl[4][4];
  #pragma unroll
  for (int mi = 0; mi < 4; mi++)
    #pragma unroll
    for (int r = 0; r < 4; r++) {
      float m = fmaxf(fmaxf(st[mi][0][r], st[mi][1][r]), fmaxf(st[mi][2][r], st[mi][3][r]));
      #pragma unroll
      for (int msk = 1; msk < 16; msk <<= 1) m = fmaxf(m, __shfl_xor(m, msk));
      float s = 0.f;
      #pragma unroll
      for (int ni = 0; ni < 4; ni++) {
        float p = __expf(st[mi][ni][r] - m);
        st[mi][ni][r] = p;
        s += p;
      }
      #pragma unroll
      for (int msk = 1; msk < 16; msk <<= 1) s += __shfl_xor(s, msk);
      invl[mi][r] = 1.0f / s;
    }

  #pragma unroll
  for (int ni = 0; ni < 4; ni++)
    #pragma unroll
    for (int mi = 0; mi < 4; mi++) {
      ushort4 pk;
      pk.x = f2b(st[mi][ni][0]); pk.y = f2b(st[mi][ni][1]);
      pk.z = f2b(st[mi][ni][2]); pk.w = f2b(st[mi][ni][3]);
      *(ushort4*)(&pt[ni * 16 + lo][mi * 16 + hi * 4]) = pk;
    }

  f4v ot[4][2];
  #pragma unroll
  for (int mi = 0; mi < 4; mi++)
    #pragma unroll
    for (int dt = 0; dt < 2; dt++) ot[mi][dt] = (f4v)(0.0f);
  #pragma unroll
  for (int kt = 0; kt < 2; kt++) {
    s8v pa[4], vb[2];
    #pragma unroll
    for (int mi = 0; mi < 4; mi++) {
      s8v p;
      #pragma unroll
      for (int e = 0; e < 8; e++) p[e] = (short)pt[kt * 32 + hi * 8 + e][mi * 16 + lo];
      pa[mi] = p;
    }
    #pragma unroll
    for (int dt = 0; dt < 2; dt++) {
      short4 a = *(const short4*)(&vt[dt * 16 + lo][kt * 32 + hi * 8]);
      short4 b = *(const short4*)(&vt[dt * 16 + lo][kt * 32 + hi * 8 + 4]);
      s8v v; v[0] = a.x; v[1] = a.y; v[2] = a.z; v[3] = a.w;
             v[4] = b.x; v[5] = b.y; v[6] = b.z; v[7] = b.w;
      vb[dt] = v;
    }
    #pragma unroll
    for (int mi = 0; mi < 4; mi++)
      #pragma unroll
      for (int dt = 0; dt < 2; dt++)
        ot[mi][dt] = __builtin_amdgcn_mfma_f32_16x16x32_bf16(pa[mi], vb[dt], ot[mi][dt], 0, 0, 0);
  }

  #pragma unroll
  for (int mi = 0; mi < 4; mi++)
    #pragma unroll
    for (int r = 0; r < 4; r++) {
      int i = mi * 16 + hi * 4 + r;
      if (i < NTOK) {
        int row = (int)rowbase + i;
        int tile = row >> 7, rl = row & 127;
        aot[tidx(tile, 6, rl, h * 32 + lo)]      = f2b(ot[mi][0][r] * invl[mi][r]);
        aot[tidx(tile, 6, rl, h * 32 + 16 + lo)] = f2b(ot[mi][1][r] * invl[mi][r]);
      }
    }
}

// ---------------- un-window + roll(+3,+3) + residual + LN2 -> X2B tiled bf16 ----------------
__global__ void k_ln2(const float* __restrict__ x, const u16* __restrict__ proj,
                      const float* __restrict__ g, const float* __restrict__ b,
                      u16* __restrict__ x2bt) {
  int wid = threadIdx.x >> 6, lane = threadIdx.x & 63;
  int r = blockIdx.x * 4 + wid;
  int tile = r >> 7, rl = r & 127;
  if (r >= M_FULL) {
    u16 z = f2b(0.0f);
    #pragma unroll
    for (int e = 0; e < 6; e++) x2bt[tidx(tile, 6, rl, lane + e * 64)] = z;
    return;
  }
  int bi = r / TOKENS, tk = r % TOKENS;
  const float* xs = x + (size_t)r * DIM;
  float v[6];
  if (tk == 0) {
    #pragma unroll
    for (int e = 0; e < 6; e++) v[e] = xs[lane + e * 64];
  } else {
    int p = tk - 1, hh = p / 56, wp = p % 56;
    int a = (hh + 53) % 56, bw = (wp + 53) % 56;   // inverse roll by +3
    int wh = a / 7, ii = a % 7, w2 = bw / 7, jj = bw % 7;
    size_t prow = ((size_t)bi * 64 + wh * 8 + w2) * NTOK + ii * 7 + jj;
    const u16* ps = proj + prow * DIM;
    #pragma unroll
    for (int e = 0; e < 6; e++) v[e] = xs[lane + e * 64] + b2f(ps[lane + e * 64]);
  }
  float s = v[0] + v[1] + v[2] + v[3] + v[4] + v[5];
  #pragma unroll
  for (int m = 1; m < 64; m <<= 1) s += __shfl_xor(s, m);
  float mu = s * (1.0f / 384.0f);
  float q = 0.f;
  #pragma unroll
  for (int e = 0; e < 6; e++) { float d = v[e] - mu; q += d * d; }
  #pragma unroll
  for (int m = 1; m < 64; m <<= 1) q += __shfl_xor(q, m);
  float rstd = rsqrtf(q * (1.0f / 384.0f) + 1e-5f);
  #pragma unroll
  for (int e = 0; e < 6; e++) {
    int c = lane + e * 64;
    x2bt[tidx(tile, 6, rl, c)] = f2b((v[e] - mu) * rstd * g[c] + b[c]);
  }
}

extern "C" void kernel_launch(void* const* d_in, const int* in_sizes, int n_in,
                              void* d_out, int out_size, void* d_ws, size_t ws_size,
                              hipStream_t stream) {
  const float* x      = (const float*)d_in[0];
  const float* n1g    = (const float*)d_in[1];
  const float* n1b    = (const float*)d_in[2];
  const float* qkv_w  = (const float*)d_in[3];
  const float* qkv_b  = (const float*)d_in[4];
  const float* rpb    = (const float*)d_in[5];
  const float* proj_w = (const float*)d_in[6];
  const float* proj_b = (const float*)d_in[7];
  const float* n2g    = (const float*)d_in[8];
  const float* n2b    = (const float*)d_in[9];
  const float* fc1_w  = (const float*)d_in[10];
  const float* fc1_b  = (const float*)d_in[11];
  const float* fc2_w  = (const float*)d_in[12];
  const float* fc2_b  = (const float*)d_in[13];
  float* outp = (float*)d_out;

  auto al = [](size_t v) { return (v + 255) & ~(size_t)255; };
  size_t base = al(884736) + al(294912) + al(1179648) + al(1179648) + al(4608)
              + al(460992) + al((size_t)M_PAD * 768);
  const int cand[3][2] = {{4, 4}, {8, 8}, {16, 16}};
  int NC1 = 16, NC2 = 16;
  for (int ci = 0; ci < 3; ci++) {
    int c1 = cand[ci][0], c2 = cand[ci][1];
    size_t cm = M_ATTN / c1;
    size_t cb_ = (785 + c2 - 1) / c2;
    size_t region = (size_t)M_ATTN * 768;                  // PROJ
    size_t fc1b = cb_ * 24 * 8192 * 2;                     // FC1 tiled
    if (fc1b > region) region = fc1b;
    size_t tot = base + 2 * al(cm * 768) + al(cm * 2304) + al(region);
    if (tot <= ws_size) { NC1 = c1; NC2 = c2; break; }
  }
  char* p = (char*)d_ws;
  auto take = [&](size_t bytes) { char* r = p; p += al(bytes); return r; };
  u16* wt_qkv  = (u16*)take(884736);
  u16* wt_proj = (u16*)take(294912);
  u16* wt_fc1  = (u16*)take(1179648);
  u16* wt_fc2  = (u16*)take(1179648);
  float* qkvb_s = (float*)take(4608);
  float* ADDt   = (float*)take(460992);
  u16* X2Bt = (u16*)take((size_t)M_PAD * 768);
  int chunkM = M_ATTN / NC1;
  u16* XWt  = (u16*)take((size_t)chunkM * 768);
  u16* QKV  = (u16*)take((size_t)chunkM * 2304);
  u16* AOt  = (u16*)take((size_t)chunkM * 768);
  int cb = (785 + NC2 - 1) / NC2;
  size_t region = (size_t)M_ATTN * 768;
  size_t fc1b = (size_t)cb * 24 * 8192 * 2;
  if (fc1b > region) region = fc1b;
  u16* PROJ = (u16*)take(region);      // aliased: PROJ dead before FC1 written
  u16* FC1t = PROJ;

  k_convert<<<2304, 256, 0, stream>>>(qkv_w, qkv_b, proj_w, fc1_w, fc2_w,
                                      wt_qkv, qkvb_s, wt_proj, wt_fc1, wt_fc2);
  k_addtab<<<451, 256, 0, stream>>>(rpb, ADDt);
  int chunkWin = chunkM / NTOK;
  for (int c = 0; c < NC1; c++) {
    int t0 = c * chunkM;
    k_ln1<<<chunkM / 4, 256, 0, stream>>>(x, n1g, n1b, XWt, t0);
    k_gemm<0><<<dim3(9, chunkM / 128), 256, 0, stream>>>(XWt, wt_qkv, qkvb_s, QKV,
                                                         nullptr, nullptr, 1152, 6, 0);
    k_attn2<<<chunkWin * HEADS / 4, 256, 0, stream>>>(QKV, ADDt, AOt, c * chunkWin);
    k_gemm<0><<<dim3(3, chunkM / 128), 256, 0, stream>>>(AOt, wt_proj, proj_b,
                                                         PROJ + (size_t)t0 * DIM,
                                                         nullptr, nullptr, 384, 6, 0);
  }
  k_ln2<<<M_PAD / 4, 256, 0, stream>>>(x, PROJ, n2g, n2b, X2Bt);
  for (int c = 0; c < NC2; c++) {
    int rb0 = c * cb;
    int nb = 785 - rb0; if (nb > cb) nb = cb; if (nb <= 0) break;
    k_gemm<1><<<dim3(12, nb), 256, 0, stream>>>(X2Bt + (size_t)rb0 * 128 * 384, wt_fc1,
                                                fc1_b, FC1t, nullptr, nullptr, 1536, 6, 0);
    k_gemm<2><<<dim3(3, nb), 256, 0, stream>>>(FC1t, wt_fc2, fc2_b, nullptr, outp, X2Bt,
                                               384, 24, rb0 * 128);
  }
}